// Round 1
// baseline (1317.584 us; speedup 1.0000x reference)
//
#include <hip/hip_runtime.h>

// GQA decode attention, split-K flash decode.
// B=32, HQ=32, HKV=8, D=128, S=4096, g=4. fp32 in/out.
#define B_     32
#define HQ_    32
#define HKV_   8
#define D_     128
#define S_     4096
#define G_     4      // HQ / HKV
#define CHUNK_ 512    // tokens per split-K chunk
#define NCH_   8      // S / CHUNK_
#define TILE_  32     // tokens per inner tile
#define VPAD_  132    // padded V row stride in LDS (floats); 132%32=4 keeps PV reads conflict-free
#define REC_   528    // floats per ws record: m[4], l[4], acc[4][128] (+pad to 16B multiple)

// One block per (b, kv_head, chunk). 256 threads = 4 waves.
// Phase 1 (all threads): 8 lanes per token; direct-global K/V float4 loads,
//   q in registers, shuffle-reduced scores -> LDS; V fragment -> LDS.
// Phase 2 (wave w owns query-group gi=w): online softmax + PV from LDS,
//   lane owns output columns {2*lane, 2*lane+1}.
__global__ __launch_bounds__(256) void attn_chunk(
    const float* __restrict__ xq, const float* __restrict__ xk,
    const float* __restrict__ xv, const float* __restrict__ kv,
    const int* __restrict__ table, const int* __restrict__ seqlen,
    float* __restrict__ ws)
{
    int idx = blockIdx.x;
    int c   = idx % NCH_;
    int tmp = idx / NCH_;
    int h   = tmp % HKV_;
    int b   = tmp / HKV_;
    int L = seqlen[b];
    int start = c * CHUNK_;
    if (start >= L) return;                 // empty chunk: record never written, never read
    int end = min(start + CHUNK_, L);

    int tid  = threadIdx.x;
    int lane = tid & 63;
    int wv   = tid >> 6;                    // wave id == gi in phase 2
    int tt   = tid >> 3;                    // token slot 0..31
    int j    = tid & 7;                     // 16-float column slice id

    __shared__ float q_sh[G_ * D_];         // 2 KiB
    __shared__ float v_sh[TILE_ * VPAD_];   // 16.5 KiB
    __shared__ float sc[G_ * TILE_];        // 0.5 KiB

    // stage q (coalesced) then pull this lane's column slice into registers
    for (int i = tid; i < G_ * D_; i += 256) {
        int gi = i >> 7, d = i & 127;
        q_sh[i] = xq[(size_t)(b * HQ_ + h * G_ + gi) * D_ + d];
    }
    __syncthreads();

    // lane j covers columns {ii*32 + j*4 .. +3}, ii = 0..3  (so global loads of
    // a token row are 8 contiguous float4s per instruction across the group)
    float qreg[G_][16];
    #pragma unroll
    for (int gi = 0; gi < G_; ++gi)
        #pragma unroll
        for (int ii = 0; ii < 4; ++ii)
            #pragma unroll
            for (int jj = 0; jj < 4; ++jj)
                qreg[gi][ii * 4 + jj] = q_sh[gi * D_ + ii * 32 + j * 4 + jj];

    float acc0 = 0.f, acc1 = 0.f;           // lane's 2 output columns for gi=wv
    float m_run = -3.0e38f, l_run = 0.f;
    const float qk_scale = 0.08838834764831845f; // 1/sqrt(128)

    const float* xk_row = xk + (size_t)(b * HKV_ + h) * D_;
    const float* xv_row = xv + (size_t)(b * HKV_ + h) * D_;

    for (int s0 = start; s0 < end; s0 += TILE_) {
        int  s_tok  = s0 + tt;
        bool valid  = s_tok < end;
        int  s_cl   = valid ? s_tok : end - 1;
        int  tok    = table[b * S_ + s_cl];
        bool is_last = (s_cl == L - 1);     // freshly-written token: take xk/xv
        const float* krow = is_last ? xk_row : kv + ((size_t)tok * (2 * HKV_) + h) * D_;
        const float* vrow = is_last ? xv_row : kv + ((size_t)tok * (2 * HKV_) + HKV_ + h) * D_;

        float4 kf[4], vf[4];
        #pragma unroll
        for (int ii = 0; ii < 4; ++ii) {
            vf[ii] = *reinterpret_cast<const float4*>(vrow + ii * 32 + j * 4);
            kf[ii] = *reinterpret_cast<const float4*>(krow + ii * 32 + j * 4);
        }

        // partial dot products for all 4 query heads of this group
        float s4[G_];
        #pragma unroll
        for (int gi = 0; gi < G_; ++gi) {
            float ss = 0.f;
            #pragma unroll
            for (int ii = 0; ii < 4; ++ii) {
                ss += kf[ii].x * qreg[gi][ii * 4 + 0];
                ss += kf[ii].y * qreg[gi][ii * 4 + 1];
                ss += kf[ii].z * qreg[gi][ii * 4 + 2];
                ss += kf[ii].w * qreg[gi][ii * 4 + 3];
            }
            s4[gi] = ss;
        }
        // reduce across the 8-lane group
        #pragma unroll
        for (int off = 1; off < 8; off <<= 1)
            #pragma unroll
            for (int gi = 0; gi < G_; ++gi)
                s4[gi] += __shfl_xor(s4[gi], off, 64);

        // stage V fragment to LDS
        #pragma unroll
        for (int ii = 0; ii < 4; ++ii)
            *reinterpret_cast<float4*>(&v_sh[tt * VPAD_ + ii * 32 + j * 4]) = vf[ii];

        // lanes j<4 publish the scores (scaled + length-masked)
        if (j < G_) {
            float val = (j == 0) ? s4[0] : (j == 1) ? s4[1] : (j == 2) ? s4[2] : s4[3];
            sc[j * TILE_ + tt] = valid ? val * qk_scale : -1.0e30f;
        }
        __syncthreads();

        // ---- phase 2: wave wv handles gi = wv ----
        float sv = sc[wv * TILE_ + (lane & 31)];       // both 32-lane halves mirror
        float tmax = sv;
        #pragma unroll
        for (int off = 1; off < 32; off <<= 1)
            tmax = fmaxf(tmax, __shfl_xor(tmax, off, 64));
        float m_new = fmaxf(m_run, tmax);
        float p     = __expf(sv - m_new);              // masked -> exp(-1e30) = 0
        float alpha = __expf(m_run - m_new);
        float tsum  = p;
        #pragma unroll
        for (int off = 1; off < 32; off <<= 1)
            tsum += __shfl_xor(tsum, off, 64);
        l_run = l_run * alpha + tsum;
        m_run = m_new;
        acc0 *= alpha;
        acc1 *= alpha;

        #pragma unroll
        for (int t = 0; t < TILE_; ++t) {
            float pt = __shfl(p, t, 64);               // p for token t lives in lane t
            float2 v2 = *reinterpret_cast<const float2*>(&v_sh[t * VPAD_ + 2 * lane]);
            acc0 += pt * v2.x;
            acc1 += pt * v2.y;
        }
        __syncthreads();
    }

    // write partial record: [m[4], l[4], acc[gi][d]]
    float* rec = ws + (size_t)blockIdx.x * REC_;
    if (lane == 0) {
        rec[wv]      = m_run;
        rec[G_ + wv] = l_run;
    }
    rec[8 + wv * D_ + 2 * lane]     = acc0;
    rec[8 + wv * D_ + 2 * lane + 1] = acc1;
}

// One block per (b, kv_head); thread = output column d; combine valid chunks.
__global__ __launch_bounds__(128) void attn_reduce(
    const float* __restrict__ ws, const int* __restrict__ seqlen,
    float* __restrict__ out)
{
    int bh = blockIdx.x;
    int h = bh % HKV_, b = bh / HKV_;
    int L = seqlen[b];
    int nch = (L + CHUNK_ - 1) / CHUNK_;
    int tid = threadIdx.x;
    const float* base = ws + (size_t)bh * NCH_ * REC_;

    #pragma unroll
    for (int gi = 0; gi < G_; ++gi) {
        float mstar = -3.0e38f;
        for (int c0 = 0; c0 < nch; ++c0)
            mstar = fmaxf(mstar, base[c0 * REC_ + gi]);
        float lsum = 0.f, osum = 0.f;
        for (int c0 = 0; c0 < nch; ++c0) {
            float w = __expf(base[c0 * REC_ + gi] - mstar);
            lsum += base[c0 * REC_ + G_ + gi] * w;
            osum += base[c0 * REC_ + 8 + gi * D_ + tid] * w;
        }
        out[(size_t)(b * HQ_ + h * G_ + gi) * D_ + tid] = osum / lsum;
    }
}

extern "C" void kernel_launch(void* const* d_in, const int* in_sizes, int n_in,
                              void* d_out, int out_size, void* d_ws, size_t ws_size,
                              hipStream_t stream)
{
    const float* xq     = (const float*)d_in[0];
    const float* xk     = (const float*)d_in[1];
    const float* xv     = (const float*)d_in[2];
    const float* kv     = (const float*)d_in[3];
    // d_in[4] = cur_select_index: implied by b_seq_len (s == L-1); unused.
    const int*   table  = (const int*)d_in[5];
    const int*   seqlen = (const int*)d_in[6];
    float* out = (float*)d_out;
    float* ws  = (float*)d_ws;   // needs B*HKV*NCH*REC*4 = ~4.33 MB

    attn_chunk<<<B_ * HKV_ * NCH_, 256, 0, stream>>>(xq, xk, xv, kv, table, seqlen, ws);
    attn_reduce<<<B_ * HKV_, 128, 0, stream>>>(ws, seqlen, out);
}